// Round 8
// baseline (1878.812 us; speedup 1.0000x reference)
//
#include <hip/hip_runtime.h>
#include <hip/hip_bf16.h>
#include <stdint.h>

// SlotAttention on MI355X. GEMMs: C[M,N] = X[M,K] @ W[N,K]^T, bf16 MFMA
// 16x16x32, fp32 acc, m97-family structure.
// R15 = R14 (1395us: BK=64 swizzled GEMM, fused GRU dual-acc kernel) +
//  1) dots+softmax FUSED (dots_sm): the BN=64 dots block's 128 rows are
//     exactly one batch's slot axis, so column-softmax runs in-kernel on an
//     LDS tile[128][65] overlaying the dead As/Bs (byte union, 33.3 KB,
//     4 blocks/CU). Kills dots_f 16MB write + 16MB read + 1 dispatch/iter.
//  2) gemm_bt __launch_bounds__(256,5): LDS 32KB x 5 = 160KB exactly;
//     VGPR 64 < 102 cap -> 5 blocks/CU for more drain-covering TLP.
// Lessons kept: R13 (BN=64 for low-K epilogue GEMMs), R12 (counted-vmcnt
// null on 2-barrier loops), R9/R10 (no 8-wave blocks / dynamic LDS).
// Workspace ~90 MB (proven-safe band).

using bf16 = __hip_bfloat16;
typedef __bf16 bf16x8 __attribute__((ext_vector_type(8)));
typedef float f32x4 __attribute__((ext_vector_type(4)));

#define F_RELU    1
#define F_SIGMOID 2
#define F_EPSC    8

__device__ __forceinline__ void gl_to_lds16(const void* g, void* l) {
  __builtin_amdgcn_global_load_lds(
      (const __attribute__((address_space(1))) uint32_t*)(uintptr_t)g,
      (__attribute__((address_space(3))) uint32_t*)(uintptr_t)l,
      16, 0, 0);
}

// Tile: 128 x BN, 4 waves as 2x2, each wave 64 x BN/2 (4 x BN/32 MFMA frags).
// LDS: row-major [rows][8 chunks of 16B], chunk XOR-swizzled by (row&7):
// writer stages source col ((t&7)^((t>>3)&7))*8 of row (t>>3)+32u into linear
// slot; reader chunk (kk*4+quad)^(lrow&7).
template <int BN>
__global__ __launch_bounds__(256, 5) void gemm_bt(
    const bf16* __restrict__ X, int ldx,
    const bf16* __restrict__ W, int ldw,
    const float* __restrict__ bias,
    int M, int N, int K, float scale, int flags,
    float* __restrict__ outF, int ldf,
    bf16* __restrict__ outB, int ldb,
    const float* __restrict__ resid,
    const float* __restrict__ auxA, // F_EPSC: c[col]
    const float* __restrict__ auxB) // F_EPSC: rowinv[row]
{
  constexpr int NJ = BN / 32;
  __shared__ __align__(16) bf16 As[128 * 64];
  __shared__ __align__(16) bf16 Bs[BN * 64];
  const int t = threadIdx.x;
  const int m0 = blockIdx.x * 128, n0 = blockIdx.y * BN;
  const int wave = t >> 6, lane = t & 63;
  const int wm = (wave >> 1) * 64, wn = (wave & 1) * (BN / 2);
  const int lrow = lane & 15, quad = lane >> 4;

  f32x4 acc[4][NJ] = {};

  const int srow = t >> 3;                        // 0..31
  const int scol = ((t & 7) ^ (srow & 7)) * 8;    // inverse-swizzled source
  const bf16* Ag = X + (size_t)(m0 + srow) * ldx + scol;
  const bf16* Bg = W + (size_t)(n0 + srow) * ldw + scol;
  bf16* Al = As + t * 8;
  bf16* Bl = Bs + t * 8;

  const int r3 = lrow & 7;
  const int c0 = quad ^ r3;          // read chunk, kk=0
  const int c1 = (4 + quad) ^ r3;    // read chunk, kk=1

  for (int k0 = 0; k0 < K; k0 += 64) {
#pragma unroll
    for (int u = 0; u < 4; ++u)
      gl_to_lds16(Ag + k0 + (size_t)(u * 32) * ldx, Al + u * 2048);
#pragma unroll
    for (int u = 0; u < NJ; ++u)
      gl_to_lds16(Bg + k0 + (size_t)(u * 32) * ldw, Bl + u * 2048);
    __syncthreads();
    const bf16x8* AS = (const bf16x8*)As;
    const bf16x8* BS = (const bf16x8*)Bs;
#pragma unroll
    for (int kk = 0; kk < 2; ++kk) {
      const int ck = kk ? c1 : c0;
      bf16x8 af[4], bfr[NJ];
#pragma unroll
      for (int i = 0; i < 4; i++)  af[i]  = AS[(wm + i * 16 + lrow) * 8 + ck];
#pragma unroll
      for (int j = 0; j < NJ; j++) bfr[j] = BS[(wn + j * 16 + lrow) * 8 + ck];
#pragma unroll
      for (int i = 0; i < 4; i++)
#pragma unroll
        for (int j = 0; j < NJ; j++)
          acc[i][j] = __builtin_amdgcn_mfma_f32_16x16x32_bf16(af[i], bfr[j], acc[i][j], 0, 0, 0);
    }
    __syncthreads();
  }

#pragma unroll
  for (int i = 0; i < 4; i++) {
    const int row0 = m0 + wm + i * 16 + quad * 4;
#pragma unroll
    for (int j = 0; j < NJ; j++) {
      const int col = n0 + wn + j * 16 + lrow;
      const float badd = bias ? bias[col] : 0.f;
#pragma unroll
      for (int r = 0; r < 4; r++) {
        const int row = row0 + r;
        float val = acc[i][j][r] * scale + badd;
        if (flags & F_EPSC)    val += 1e-8f * auxA[col] * auxB[row];
        if (flags & F_RELU)    val = fmaxf(val, 0.f);
        if (flags & F_SIGMOID) val = 1.f / (1.f + expf(-val));
        if (resid) val += resid[(size_t)row * ldf + col];
        if (outF) outF[(size_t)row * ldf + col] = val;
        if (outB) outB[(size_t)row * ldb + col] = __float2bfloat16(val);
      }
    }
  }
}

// Fused dots+softmax: per (b=blockIdx.x, jt=blockIdx.y) computes the
// 128x64 tile dots = SCALE*(xln @ kq^T) + bqk (K=1024), then column-softmax
// over the 128 slot rows IN-KERNEL (LDS tile overlays dead As/Bs), writing
// bf16 softmax to xcat2 cols [0,512) + row partials P[m][8].
__global__ __launch_bounds__(256, 4) void dots_sm(
    const bf16* __restrict__ X,     // xln, ld 1024
    const bf16* __restrict__ Wk,    // kq,  ld 1024
    const float* __restrict__ bqk,  // [512]
    float scale,
    bf16* __restrict__ xcat2, float* __restrict__ P)
{
  // union: K-loop uses As(16K)+Bs(8K); epilogue uses tile[128][65] f32 (33.3K)
  __shared__ __align__(16) char usm[128 * 65 * 4];
  __shared__ float cred[4][64];
  __shared__ float colmax[64], colinv[64];
  bf16* As = (bf16*)usm;
  bf16* Bs = (bf16*)(usm + 16384);
  const int t = threadIdx.x;
  const int m0 = blockIdx.x * 128, n0 = blockIdx.y * 64;
  const int wave = t >> 6, lane = t & 63;
  const int wm = (wave >> 1) * 64, wn = (wave & 1) * 32;
  const int lrow = lane & 15, quad = lane >> 4;

  f32x4 acc[4][2] = {};

  const int srow = t >> 3;
  const int scol = ((t & 7) ^ (srow & 7)) * 8;
  const bf16* Ag = X + (size_t)(m0 + srow) * 1024 + scol;
  const bf16* Bg = Wk + (size_t)(n0 + srow) * 1024 + scol;
  bf16* Al = As + t * 8;
  bf16* Bl = Bs + t * 8;

  const int r3 = lrow & 7;
  const int c0 = quad ^ r3;
  const int c1 = (4 + quad) ^ r3;

  for (int k0 = 0; k0 < 1024; k0 += 64) {
#pragma unroll
    for (int u = 0; u < 4; ++u)
      gl_to_lds16(Ag + k0 + (size_t)(u * 32) * 1024, Al + u * 2048);
#pragma unroll
    for (int u = 0; u < 2; ++u)
      gl_to_lds16(Bg + k0 + (size_t)(u * 32) * 1024, Bl + u * 2048);
    __syncthreads();
    const bf16x8* AS = (const bf16x8*)As;
    const bf16x8* BS = (const bf16x8*)Bs;
#pragma unroll
    for (int kk = 0; kk < 2; ++kk) {
      const int ck = kk ? c1 : c0;
      bf16x8 af[4], bfr[2];
#pragma unroll
      for (int i = 0; i < 4; i++) af[i] = AS[(wm + i * 16 + lrow) * 8 + ck];
#pragma unroll
      for (int j = 0; j < 2; j++) bfr[j] = BS[(wn + j * 16 + lrow) * 8 + ck];
#pragma unroll
      for (int i = 0; i < 4; i++)
#pragma unroll
        for (int j = 0; j < 2; j++)
          acc[i][j] = __builtin_amdgcn_mfma_f32_16x16x32_bf16(af[i], bfr[j], acc[i][j], 0, 0, 0);
    }
    __syncthreads();
  }

  // acc -> tile (scale + bias). As/Bs dead (loop ended on a barrier).
  float (*tile)[65] = (float(*)[65])usm;
#pragma unroll
  for (int i = 0; i < 4; i++) {
    const int rl0 = wm + i * 16 + quad * 4;
#pragma unroll
    for (int j = 0; j < 2; j++) {
      const int cl = wn + j * 16 + lrow;
      const float badd = bqk[n0 + cl];
#pragma unroll
      for (int r = 0; r < 4; r++)
        tile[rl0 + r][cl] = acc[i][j][r] * scale + badd;
    }
  }
  __syncthreads();

  // column-softmax over the 128 slot rows (identical to softmax_fused body)
  const int c = t & 63, s = t >> 6;
  float mx = -1e30f;
  for (int i = s * 32; i < s * 32 + 32; i++) mx = fmaxf(mx, tile[i][c]);
  cred[s][c] = mx;
  __syncthreads();
  if (s == 0) colmax[c] = fmaxf(fmaxf(cred[0][c], cred[1][c]),
                                fmaxf(cred[2][c], cred[3][c]));
  __syncthreads();
  const float cm = colmax[c];
  float sum = 0.f;
  for (int i = s * 32; i < s * 32 + 32; i++) {
    const float e = expf(tile[i][c] - cm);
    tile[i][c] = e; sum += e;
  }
  cred[s][c] = sum;
  __syncthreads();
  if (s == 0) colinv[c] = 1.f / (cred[0][c] + cred[1][c] + cred[2][c] + cred[3][c]);
  __syncthreads();
  bf16* dst = xcat2 + (size_t)blockIdx.x * 128 * 1536 + blockIdx.y * 64;
#pragma unroll
  for (int p = 0; p < 32; p++) {
    const int i = p * 4 + (t >> 6), cc = t & 63;
    dst[(size_t)i * 1536 + cc] = __float2bfloat16(tile[i][cc] * colinv[cc]);
  }
  if (t < 128) {
    float rs = 0.f;
    for (int cc = 0; cc < 64; cc++) rs += tile[t][cc] * colinv[cc];
    P[((size_t)blockIdx.x * 128 + t) * 8 + blockIdx.y] = rs;
  }
}

// Fused GRU: per 128x64 tile of the [8192 x 1024] update,
//   accN = xcat2[:, 0:512)    @ PTn^T  (i_n pre-act, K=512)
//   accH = xcat2[:, 512:1536) @ Whn^T  (h_n pre-act, K=1024)
// via one B panel Wc = [PTn | Whn] (1024 x 1536, ld 1536). Epilogue:
//   n = tanh(accN + bihn + eps*cn*rinv + r*(accH + bhhn));
//   slots = (1-z)*n + z*prev   (r,z from rz_b; prev from slots_f)
__global__ __launch_bounds__(256, 4) void gemm_gru(
    const bf16* __restrict__ X,     // xcat2, ld 1536
    const bf16* __restrict__ Wc,    // [PTn|Whn], ld 1536
    const float* __restrict__ bihn,
    const float* __restrict__ bhhn,
    const float* __restrict__ cn,   // c[col] (n-gate third)
    const float* __restrict__ rinv, // rowinv[row]
    const bf16* __restrict__ rz,    // sigmoided r|z, ld 2048
    float* __restrict__ slots)      // resid in, out (ld 1024)
{
  __shared__ __align__(16) bf16 As[128 * 64];
  __shared__ __align__(16) bf16 Bs[64 * 64];
  const int t = threadIdx.x;
  const int m0 = blockIdx.x * 128, n0 = blockIdx.y * 64;
  const int wave = t >> 6, lane = t & 63;
  const int wm = (wave >> 1) * 64, wn = (wave & 1) * 32;
  const int lrow = lane & 15, quad = lane >> 4;

  f32x4 accN[4][2] = {};
  f32x4 accH[4][2] = {};

  const int srow = t >> 3;
  const int scol = ((t & 7) ^ (srow & 7)) * 8;
  const bf16* Ag = X + (size_t)(m0 + srow) * 1536 + scol;
  const bf16* Bg = Wc + (size_t)(n0 + srow) * 1536 + scol;
  bf16* Al = As + t * 8;
  bf16* Bl = Bs + t * 8;

  const int r3 = lrow & 7;
  const int c0 = quad ^ r3;
  const int c1 = (4 + quad) ^ r3;

  // ---- phase N: K = [0, 512) -> accN ----
  for (int k0 = 0; k0 < 512; k0 += 64) {
#pragma unroll
    for (int u = 0; u < 4; ++u)
      gl_to_lds16(Ag + k0 + (size_t)(u * 32) * 1536, Al + u * 2048);
#pragma unroll
    for (int u = 0; u < 2; ++u)
      gl_to_lds16(Bg + k0 + (size_t)(u * 32) * 1536, Bl + u * 2048);
    __syncthreads();
    const bf16x8* AS = (const bf16x8*)As;
    const bf16x8* BS = (const bf16x8*)Bs;
#pragma unroll
    for (int kk = 0; kk < 2; ++kk) {
      const int ck = kk ? c1 : c0;
      bf16x8 af[4], bfr[2];
#pragma unroll
      for (int i = 0; i < 4; i++) af[i] = AS[(wm + i * 16 + lrow) * 8 + ck];
#pragma unroll
      for (int j = 0; j < 2; j++) bfr[j] = BS[(wn + j * 16 + lrow) * 8 + ck];
#pragma unroll
      for (int i = 0; i < 4; i++)
#pragma unroll
        for (int j = 0; j < 2; j++)
          accN[i][j] = __builtin_amdgcn_mfma_f32_16x16x32_bf16(af[i], bfr[j], accN[i][j], 0, 0, 0);
    }
    __syncthreads();
  }
  // ---- phase H: K = [512, 1536) -> accH ----
  for (int k0 = 512; k0 < 1536; k0 += 64) {
#pragma unroll
    for (int u = 0; u < 4; ++u)
      gl_to_lds16(Ag + k0 + (size_t)(u * 32) * 1536, Al + u * 2048);
#pragma unroll
    for (int u = 0; u < 2; ++u)
      gl_to_lds16(Bg + k0 + (size_t)(u * 32) * 1536, Bl + u * 2048);
    __syncthreads();
    const bf16x8* AS = (const bf16x8*)As;
    const bf16x8* BS = (const bf16x8*)Bs;
#pragma unroll
    for (int kk = 0; kk < 2; ++kk) {
      const int ck = kk ? c1 : c0;
      bf16x8 af[4], bfr[2];
#pragma unroll
      for (int i = 0; i < 4; i++) af[i] = AS[(wm + i * 16 + lrow) * 8 + ck];
#pragma unroll
      for (int j = 0; j < 2; j++) bfr[j] = BS[(wn + j * 16 + lrow) * 8 + ck];
#pragma unroll
      for (int i = 0; i < 4; i++)
#pragma unroll
        for (int j = 0; j < 2; j++)
          accH[i][j] = __builtin_amdgcn_mfma_f32_16x16x32_bf16(af[i], bfr[j], accH[i][j], 0, 0, 0);
    }
    __syncthreads();
  }

#pragma unroll
  for (int i = 0; i < 4; i++) {
    const int row0 = m0 + wm + i * 16 + quad * 4;
#pragma unroll
    for (int j = 0; j < 2; j++) {
      const int col = n0 + wn + j * 16 + lrow;
      const float bN = bihn[col];
      const float bH = bhhn[col];
      const float cc = cn[col];
#pragma unroll
      for (int r = 0; r < 4; r++) {
        const int row = row0 + r;
        const size_t ridx = (size_t)row * 1024 + col;
        const float vn = accN[i][j][r] + bN + 1e-8f * cc * rinv[row];
        const float vh = accH[i][j][r] + bH;
        const float rg = __bfloat162float(rz[(size_t)row * 2048 + col]);
        const float zg = __bfloat162float(rz[(size_t)row * 2048 + 1024 + col]);
        const float ng = tanhf(vn + rg * vh);
        const float prev = slots[ridx];
        slots[ridx] = (1.f - zg) * ng + zg * prev;
      }
    }
  }
}

// LayerNorm over D=1024, one block per row, bf16 out (stride ldo).
__global__ __launch_bounds__(256) void ln_rows(const float* __restrict__ x,
    const float* __restrict__ g, const float* __restrict__ b,
    bf16* __restrict__ out, int ldo)
{
  const int row = blockIdx.x;
  const int t = threadIdx.x;
  const float* xr = x + (size_t)row * 1024;
  float v[4];
  float s = 0.f, s2 = 0.f;
#pragma unroll
  for (int i = 0; i < 4; i++) {
    float val = xr[t + 256 * i];
    v[i] = val; s += val; s2 += val * val;
  }
#pragma unroll
  for (int off = 32; off > 0; off >>= 1) {
    s  += __shfl_down(s, off);
    s2 += __shfl_down(s2, off);
  }
  __shared__ float rs[4], rs2[4];
  if ((t & 63) == 0) { rs[t >> 6] = s; rs2[t >> 6] = s2; }
  __syncthreads();
  const float S  = rs[0] + rs[1] + rs[2] + rs[3];
  const float S2 = rs2[0] + rs2[1] + rs2[2] + rs2[3];
  const float mean = S * (1.f / 1024.f);
  const float var  = S2 * (1.f / 1024.f) - mean * mean;
  const float rstd = rsqrtf(var + 1e-5f);
  bf16* outr = out + (size_t)row * ldo;
#pragma unroll
  for (int i = 0; i < 4; i++) {
    const int c = t + 256 * i;
    outr[c] = __float2bfloat16((v[i] - mean) * rstd * g[c] + b[c]);
  }
}

// rowinv[m] = 1 / (sum_jt P[m][jt] + 512e-8)
__global__ __launch_bounds__(256) void rowinv_k(const float* __restrict__ P,
                                                float* __restrict__ rowinv)
{
  const int m = blockIdx.x * 256 + threadIdx.x;
  const float* p = P + (size_t)m * 8;
  float s = 0.f;
#pragma unroll
  for (int i = 0; i < 8; i++) s += p[i];
  rowinv[m] = 1.f / (s + 512.f * 1e-8f);
}

// xcat2 sm-columns *= rowinv[m]  (in-place, cols [0,512))
__global__ __launch_bounds__(256) void smscale(bf16* __restrict__ x,
                                               const float* __restrict__ rinv)
{
  const int idx = blockIdx.x * 256 + threadIdx.x;  // M*512
  const int m = idx >> 9, j = idx & 511;
  const size_t a = (size_t)m * 1536 + j;
  x[a] = __float2bfloat16(__bfloat162float(x[a]) * rinv[m]);
}

// slots init: fp32 master + bf16 mirror into xcat2 cols [512,1536).
__global__ __launch_bounds__(256) void init_slots(const float* __restrict__ x,
    float* __restrict__ sf, bf16* __restrict__ xr)
{
  const size_t base = (size_t)blockIdx.x * 1024 + threadIdx.x;
#pragma unroll
  for (int i = 0; i < 4; i++) {
    const size_t idx = base + 256 * i;
    const float v = x[idx];
    sf[idx] = v;
    xr[(idx >> 10) * 1536 + (idx & 1023)] = __float2bfloat16(v);
  }
}

__global__ __launch_bounds__(256) void f2b(const float* __restrict__ x,
                                           bf16* __restrict__ y)
{
  const size_t base = (size_t)blockIdx.x * 1024 + threadIdx.x;
#pragma unroll
  for (int i = 0; i < 4; i++) y[base + 256 * i] = __float2bfloat16(x[base + 256 * i]);
}

// strided f2b: dst[n*dstld + c] = src[n*1024 + c]  (n rows x 1024 cols)
__global__ __launch_bounds__(256) void f2b_ld(const float* __restrict__ src,
                                              bf16* __restrict__ dst, int dstld)
{
  const int idx = blockIdx.x * 256 + threadIdx.x;
  const int n = idx >> 10, c = idx & 1023;
  dst[(size_t)n * dstld + c] = __float2bfloat16(src[(size_t)n * 1024 + c]);
}

// wqT[d][d'] = Wq[d'][d]
__global__ __launch_bounds__(256) void f2b_T(const float* __restrict__ Wq,
                                             bf16* __restrict__ wqT)
{
  const int idx = blockIdx.x * 256 + threadIdx.x;
  const int d = idx >> 10, dp = idx & 1023;
  wqT[idx] = __float2bfloat16(Wq[(size_t)dp * 1024 + d]);
}

__global__ __launch_bounds__(256) void make_brz(const float* __restrict__ bih,
    const float* __restrict__ bhh, float* __restrict__ brz)
{
  const int n = blockIdx.x * 256 + threadIdx.x;
  brz[n] = bih[n] + bhh[n];
}

// bqk[j] = SCALE * <bq, k[j,:]>
__global__ __launch_bounds__(256) void make_bqk(const bf16* __restrict__ k,
    const float* __restrict__ bq, float* __restrict__ bqk, float scale)
{
  const int j = blockIdx.x * 256 + threadIdx.x;
  const bf16* kr = k + (size_t)j * 1024;
  float s = 0.f;
  for (int d = 0; d < 1024; d++) s += bq[d] * __bfloat162float(kr[d]);
  bqk[j] = scale * s;
}

// vcol[d] = sum_j v[j,d]   (v row-major [512][1024])
__global__ __launch_bounds__(256) void make_vcol(const bf16* __restrict__ v,
                                                 float* __restrict__ vcol)
{
  const int d = blockIdx.x * 256 + threadIdx.x;  // 1024
  float s = 0.f;
  for (int j = 0; j < 512; j++) s += __bfloat162float(v[(size_t)j * 1024 + d]);
  vcol[d] = s;
}

// c[n] = sum_d Wih[n,d] * vcol[d]  (block per n, 3072 blocks)
__global__ __launch_bounds__(256) void make_c(const float* __restrict__ Wih,
    const float* __restrict__ vcol, float* __restrict__ c)
{
  const int n = blockIdx.x;
  const int t = threadIdx.x;
  const float* wr = Wih + (size_t)n * 1024;
  float s = 0.f;
#pragma unroll
  for (int i = 0; i < 4; i++) s += wr[t + 256 * i] * vcol[t + 256 * i];
#pragma unroll
  for (int off = 32; off > 0; off >>= 1) s += __shfl_down(s, off);
  __shared__ float rs[4];
  if ((t & 63) == 0) rs[t >> 6] = s;
  __syncthreads();
  if (t == 0) c[n] = rs[0] + rs[1] + rs[2] + rs[3];
}

extern "C" void kernel_launch(void* const* d_in, const int* in_sizes, int n_in,
                              void* d_out, int out_size, void* d_ws, size_t ws_size,
                              hipStream_t stream)
{
  const float* inputs = (const float*)d_in[0];
  const float* texts  = (const float*)d_in[1];
  const float* Wq  = (const float*)d_in[2];  const float* bq  = (const float*)d_in[3];
  const float* Wk  = (const float*)d_in[4];  const float* bk  = (const float*)d_in[5];
  const float* Wv  = (const float*)d_in[6];  const float* bv  = (const float*)d_in[7];
  const float* Wih = (const float*)d_in[8];  const float* bih = (const float*)d_in[9];
  const float* Whh = (const float*)d_in[10]; const float* bhh = (const float*)d_in[11];
  const float* W1  = (const float*)d_in[12]; const float* b1  = (const float*)d_in[13];
  const float* W2  = (const float*)d_in[14]; const float* b2  = (const float*)d_in[15];
  const float* g_in = (const float*)d_in[16]; const float* be_in = (const float*)d_in[17];
  const float* g_sl = (const float*)d_in[18]; const float* be_sl = (const float*)d_in[19];
  const float* g_ff = (const float*)d_in[20]; const float* be_ff = (const float*)d_in[21];

  constexpr int B = 64, N = 128, J = 512, D = 1024, H = 4096;
  constexpr int M = B * N;
  const float SCALE = 0.03125f;

  char* ws = (char*)d_ws;
  size_t off = 0;
  auto alloc = [&](size_t bytes) -> char* {
    char* p = ws + off; off += (bytes + 255) & ~(size_t)255; return p;
  };
  // persistent (~66 MB)
  bf16* wk_b    = (bf16*)alloc((size_t)D * D * 2);         // 2 MB
  bf16* wv_b    = (bf16*)alloc((size_t)D * D * 2);         // 2 MB
  bf16* w1_b    = (bf16*)alloc((size_t)H * D * 2);         // 8 MB
  bf16* w2_b    = (bf16*)alloc((size_t)D * H * 2);         // 8 MB
  bf16* win_b   = (bf16*)alloc((size_t)D * D * 2);         // 2 MB Wih rows 2048:3071
  bf16* wihrz_b = (bf16*)alloc((size_t)2048 * D * 2);      // 4 MB Wih rows 0:2047
  bf16* wqT_b   = (bf16*)alloc((size_t)D * D * 2);         // 2 MB
  bf16* wcat2_b = (bf16*)alloc((size_t)2048 * 1536 * 2);   // 6 MB [PT_rz|Whh_rz]
  bf16* ptnw_b  = (bf16*)alloc((size_t)D * 1536 * 2);      // 3 MB [PT_n|Whn]
  bf16* kq_b    = (bf16*)alloc((size_t)J * D * 2);         // 1 MB
  bf16* texts_n = (bf16*)alloc((size_t)J * D * 2);         // 1 MB
  bf16* k_b     = (bf16*)alloc((size_t)J * D * 2);         // 1 MB
  bf16* v_b     = (bf16*)alloc((size_t)J * D * 2);         // 1 MB
  bf16* xcat2_b = (bf16*)alloc((size_t)M * 1536 * 2);      // 24 MB [sm|slots]
  float* brz_b  = (float*)alloc((size_t)2048 * 4);
  float* bqk_b  = (float*)alloc((size_t)J * 4);
  float* vcol_b = (float*)alloc((size_t)D * 4);
  float* c_b    = (float*)alloc((size_t)3072 * 4);
  float* P_b    = (float*)alloc((size_t)M * 8 * 4);
  float* rinv_b = (float*)alloc((size_t)M * 4);
  // phase-overlapped union U (48 MB):
  //   xln (16 MB) at U      — live ln->dots_sm (attn) / ln->W1/W2 (mlp)
  //   rz  (32 MB) at U      — live rzGEMM->gru (xln dead by then)
  //   h1  (32 MB) at U+16MB — live W1->W2 (rz dead by then)
  char* U = alloc((size_t)48 * 1024 * 1024);
  bf16*  xln_b  = (bf16*)(U);
  bf16*  rz_b   = (bf16*)(U);
  bf16*  h1_b   = (bf16*)(U + (size_t)16 * 1024 * 1024);

  if (ws_size < off) return;  // fail loudly instead of faulting

  float* slots_f = (float*)d_out;

  // ---- weight prep ----
  f2b<<<dim3(D * D / 1024), 256, 0, stream>>>(Wk, wk_b);
  f2b<<<dim3(D * D / 1024), 256, 0, stream>>>(Wv, wv_b);
  f2b<<<dim3(H * D / 1024), 256, 0, stream>>>(W1, w1_b);
  f2b<<<dim3(D * H / 1024), 256, 0, stream>>>(W2, w2_b);
  f2b<<<dim3(D * D / 1024), 256, 0, stream>>>(Wih + (size_t)2048 * D, win_b);
  f2b<<<dim3(2048 * D / 1024), 256, 0, stream>>>(Wih, wihrz_b);
  f2b_T<<<dim3(D * D / 256), 256, 0, stream>>>(Wq, wqT_b);
  // Whh rows 0:2047 -> wcat2 cols [512,1536)
  f2b_ld<<<dim3(2048 * 1024 / 256), 256, 0, stream>>>(Whh, wcat2_b + 512, 1536);
  // Whh rows 2048:3071 (Whn) -> ptnw cols [512,1536)
  f2b_ld<<<dim3(1024 * 1024 / 256), 256, 0, stream>>>(
      Whh + (size_t)2048 * D, ptnw_b + 512, 1536);
  make_brz<<<dim3(8), 256, 0, stream>>>(bih, bhh, brz_b);

  init_slots<<<dim3(M * D / 1024), 256, 0, stream>>>(inputs, slots_f, xcat2_b + 512);

  // ---- iteration-invariant tensors ----
  ln_rows<<<dim3(J), 256, 0, stream>>>(texts, g_in, be_in, texts_n, D);
  gemm_bt<64><<<dim3(J / 128, D / 64), 256, 0, stream>>>(
      texts_n, D, wk_b, D, bk, J, D, D, 1.f, 0,
      nullptr, 0, k_b, D, nullptr, nullptr, nullptr);
  gemm_bt<64><<<dim3(J / 128, D / 64), 256, 0, stream>>>(
      texts_n, D, wv_b, D, bv, J, D, D, 1.f, 0,
      nullptr, 0, v_b, D, nullptr, nullptr, nullptr);
  gemm_bt<64><<<dim3(J / 128, D / 64), 256, 0, stream>>>(
      k_b, D, wqT_b, D, nullptr, J, D, D, 1.f, 0,
      nullptr, 0, kq_b, D, nullptr, nullptr, nullptr);
  // PT_rz = Wih_rz @ v^T -> wcat2 cols [0,512)
  gemm_bt<64><<<dim3(2048 / 128, J / 64), 256, 0, stream>>>(
      wihrz_b, D, v_b, D, nullptr, 2048, J, D, 1.f, 0,
      nullptr, 0, wcat2_b, 1536, nullptr, nullptr, nullptr);
  // PT_n = Wih_n @ v^T -> ptnw cols [0,512)
  gemm_bt<64><<<dim3(D / 128, J / 64), 256, 0, stream>>>(
      win_b, D, v_b, D, nullptr, D, J, D, 1.f, 0,
      nullptr, 0, ptnw_b, 1536, nullptr, nullptr, nullptr);
  make_bqk<<<dim3(2), 256, 0, stream>>>(k_b, bq, bqk_b, SCALE);
  make_vcol<<<dim3(4), 256, 0, stream>>>(v_b, vcol_b);
  make_c<<<dim3(3072), 256, 0, stream>>>(Wih, vcol_b, c_b);

  for (int it = 0; it < 3; it++) {
    // xln = LN(slots)
    ln_rows<<<dim3(M), 256, 0, stream>>>(slots_f, g_sl, be_sl, xln_b, D);
    // fused dots+softmax -> xcat2 cols [0,512) + P partials
    dots_sm<<<dim3(M / 128, J / 64), 256, 0, stream>>>(
        xln_b, kq_b, bqk_b, SCALE, xcat2_b, P_b);
    rowinv_k<<<dim3(M / 256), 256, 0, stream>>>(P_b, rinv_b);
    smscale<<<dim3(M * 512 / 256), 256, 0, stream>>>(xcat2_b, rinv_b);
    // rz = sigmoid([sm2|slots] @ [PT_rz|Whh_rz]^T + brz + eps*rinv*c_rz)
    // (xln dead now; rz overlays U)
    gemm_bt<128><<<dim3(M / 128, 2048 / 128), 256, 0, stream>>>(
        xcat2_b, 1536, wcat2_b, 1536, brz_b, M, 2048, 1536, 1.f, F_SIGMOID | F_EPSC,
        nullptr, 0, rz_b, 2048, nullptr, c_b, rinv_b);
    // fused GRU: accN (sm2@PTn) + accH (slots@Whn) + gate epilogue -> slots_f
    gemm_gru<<<dim3(M / 128, D / 64), 256, 0, stream>>>(
        xcat2_b, ptnw_b, bih + 2048, bhh + 2048, c_b + 2048, rinv_b,
        rz_b, slots_f);
    // MLP residual, H split into two 2048 halves (rz dead after gru)
    ln_rows<<<dim3(M), 256, 0, stream>>>(slots_f, g_ff, be_ff, xln_b, D);
    gemm_bt<128><<<dim3(M / 128, 2048 / 128), 256, 0, stream>>>(
        xln_b, D, w1_b, D, b1, M, 2048, D, 1.f, F_RELU,
        nullptr, 0, h1_b, 2048, nullptr, nullptr, nullptr);
    gemm_bt<64><<<dim3(M / 128, D / 64), 256, 0, stream>>>(
        h1_b, 2048, w2_b, H, b2, M, D, 2048, 1.f, 0,
        slots_f, D, nullptr, 0, slots_f, nullptr, nullptr);
    gemm_bt<128><<<dim3(M / 128, 2048 / 128), 256, 0, stream>>>(
        xln_b, D, w1_b + (size_t)2048 * D, D, b1 + 2048, M, 2048, D, 1.f, F_RELU,
        nullptr, 0, h1_b, 2048, nullptr, nullptr, nullptr);
    gemm_bt<64><<<dim3(M / 128, D / 64), 256, 0, stream>>>(
        h1_b, 2048, w2_b + 2048, H, nullptr, M, D, 2048, 1.f, 0,
        slots_f, D, xcat2_b + 512, 1536, slots_f, nullptr, nullptr);
  }
}

// Round 9
// 1352.114 us; speedup vs baseline: 1.3895x; 1.3895x over previous
//
#include <hip/hip_runtime.h>
#include <hip/hip_bf16.h>
#include <stdint.h>

// SlotAttention on MI355X. GEMMs: C[M,N] = X[M,K] @ W[N,K]^T, bf16 MFMA
// 16x16x32, fp32 acc, m97-family structure.
// R16 = R15 with the ONE poisoned change reverted: gemm_bt back to
// __launch_bounds__(256,4). R15's (256,5) capped VGPR at 48 < the 64 the
// BN=128 accumulators need -> scratch spill (WRITE_SIZE 33->300 MB,
// MfmaUtil 30->13%, dur 72->159us). Guideline 6: never trade registers
// for occupancy past the spill cliff.
// Kept from R15: dots+softmax fused (dots_sm, kills dots_f 16MB write +
// 16MB read + 1 dispatch/iter). Kept from R14: fused GRU dual-acc kernel.
// Lessons: R13 (BN=64 for low-K epilogue GEMMs), R12 (counted-vmcnt null),
// R9/R10 (no 8-wave blocks / no dynamic LDS).
// Workspace ~90 MB (proven-safe band).

using bf16 = __hip_bfloat16;
typedef __bf16 bf16x8 __attribute__((ext_vector_type(8)));
typedef float f32x4 __attribute__((ext_vector_type(4)));

#define F_RELU    1
#define F_SIGMOID 2
#define F_EPSC    8

__device__ __forceinline__ void gl_to_lds16(const void* g, void* l) {
  __builtin_amdgcn_global_load_lds(
      (const __attribute__((address_space(1))) uint32_t*)(uintptr_t)g,
      (__attribute__((address_space(3))) uint32_t*)(uintptr_t)l,
      16, 0, 0);
}

// Tile: 128 x BN, 4 waves as 2x2, each wave 64 x BN/2 (4 x BN/32 MFMA frags).
// LDS: row-major [rows][8 chunks of 16B], chunk XOR-swizzled by (row&7):
// writer stages source col ((t&7)^((t>>3)&7))*8 of row (t>>3)+32u into linear
// slot; reader chunk (kk*4+quad)^(lrow&7).
template <int BN>
__global__ __launch_bounds__(256, 4) void gemm_bt(
    const bf16* __restrict__ X, int ldx,
    const bf16* __restrict__ W, int ldw,
    const float* __restrict__ bias,
    int M, int N, int K, float scale, int flags,
    float* __restrict__ outF, int ldf,
    bf16* __restrict__ outB, int ldb,
    const float* __restrict__ resid,
    const float* __restrict__ auxA, // F_EPSC: c[col]
    const float* __restrict__ auxB) // F_EPSC: rowinv[row]
{
  constexpr int NJ = BN / 32;
  __shared__ __align__(16) bf16 As[128 * 64];
  __shared__ __align__(16) bf16 Bs[BN * 64];
  const int t = threadIdx.x;
  const int m0 = blockIdx.x * 128, n0 = blockIdx.y * BN;
  const int wave = t >> 6, lane = t & 63;
  const int wm = (wave >> 1) * 64, wn = (wave & 1) * (BN / 2);
  const int lrow = lane & 15, quad = lane >> 4;

  f32x4 acc[4][NJ] = {};

  const int srow = t >> 3;                        // 0..31
  const int scol = ((t & 7) ^ (srow & 7)) * 8;    // inverse-swizzled source
  const bf16* Ag = X + (size_t)(m0 + srow) * ldx + scol;
  const bf16* Bg = W + (size_t)(n0 + srow) * ldw + scol;
  bf16* Al = As + t * 8;
  bf16* Bl = Bs + t * 8;

  const int r3 = lrow & 7;
  const int c0 = quad ^ r3;          // read chunk, kk=0
  const int c1 = (4 + quad) ^ r3;    // read chunk, kk=1

  for (int k0 = 0; k0 < K; k0 += 64) {
#pragma unroll
    for (int u = 0; u < 4; ++u)
      gl_to_lds16(Ag + k0 + (size_t)(u * 32) * ldx, Al + u * 2048);
#pragma unroll
    for (int u = 0; u < NJ; ++u)
      gl_to_lds16(Bg + k0 + (size_t)(u * 32) * ldw, Bl + u * 2048);
    __syncthreads();
    const bf16x8* AS = (const bf16x8*)As;
    const bf16x8* BS = (const bf16x8*)Bs;
#pragma unroll
    for (int kk = 0; kk < 2; ++kk) {
      const int ck = kk ? c1 : c0;
      bf16x8 af[4], bfr[NJ];
#pragma unroll
      for (int i = 0; i < 4; i++)  af[i]  = AS[(wm + i * 16 + lrow) * 8 + ck];
#pragma unroll
      for (int j = 0; j < NJ; j++) bfr[j] = BS[(wn + j * 16 + lrow) * 8 + ck];
#pragma unroll
      for (int i = 0; i < 4; i++)
#pragma unroll
        for (int j = 0; j < NJ; j++)
          acc[i][j] = __builtin_amdgcn_mfma_f32_16x16x32_bf16(af[i], bfr[j], acc[i][j], 0, 0, 0);
    }
    __syncthreads();
  }

#pragma unroll
  for (int i = 0; i < 4; i++) {
    const int row0 = m0 + wm + i * 16 + quad * 4;
#pragma unroll
    for (int j = 0; j < NJ; j++) {
      const int col = n0 + wn + j * 16 + lrow;
      const float badd = bias ? bias[col] : 0.f;
#pragma unroll
      for (int r = 0; r < 4; r++) {
        const int row = row0 + r;
        float val = acc[i][j][r] * scale + badd;
        if (flags & F_EPSC)    val += 1e-8f * auxA[col] * auxB[row];
        if (flags & F_RELU)    val = fmaxf(val, 0.f);
        if (flags & F_SIGMOID) val = 1.f / (1.f + expf(-val));
        if (resid) val += resid[(size_t)row * ldf + col];
        if (outF) outF[(size_t)row * ldf + col] = val;
        if (outB) outB[(size_t)row * ldb + col] = __float2bfloat16(val);
      }
    }
  }
}

// Fused dots+softmax: per (b=blockIdx.x, jt=blockIdx.y) computes the
// 128x64 tile dots = SCALE*(xln @ kq^T) + bqk (K=1024), then column-softmax
// over the 128 slot rows IN-KERNEL (LDS tile overlays dead As/Bs), writing
// bf16 softmax to xcat2 cols [0,512) + row partials P[m][8].
__global__ __launch_bounds__(256, 4) void dots_sm(
    const bf16* __restrict__ X,     // xln, ld 1024
    const bf16* __restrict__ Wk,    // kq,  ld 1024
    const float* __restrict__ bqk,  // [512]
    float scale,
    bf16* __restrict__ xcat2, float* __restrict__ P)
{
  // union: K-loop uses As(16K)+Bs(8K); epilogue uses tile[128][65] f32 (33.3K)
  __shared__ __align__(16) char usm[128 * 65 * 4];
  __shared__ float cred[4][64];
  __shared__ float colmax[64], colinv[64];
  bf16* As = (bf16*)usm;
  bf16* Bs = (bf16*)(usm + 16384);
  const int t = threadIdx.x;
  const int m0 = blockIdx.x * 128, n0 = blockIdx.y * 64;
  const int wave = t >> 6, lane = t & 63;
  const int wm = (wave >> 1) * 64, wn = (wave & 1) * 32;
  const int lrow = lane & 15, quad = lane >> 4;

  f32x4 acc[4][2] = {};

  const int srow = t >> 3;
  const int scol = ((t & 7) ^ (srow & 7)) * 8;
  const bf16* Ag = X + (size_t)(m0 + srow) * 1024 + scol;
  const bf16* Bg = Wk + (size_t)(n0 + srow) * 1024 + scol;
  bf16* Al = As + t * 8;
  bf16* Bl = Bs + t * 8;

  const int r3 = lrow & 7;
  const int c0 = quad ^ r3;
  const int c1 = (4 + quad) ^ r3;

  for (int k0 = 0; k0 < 1024; k0 += 64) {
#pragma unroll
    for (int u = 0; u < 4; ++u)
      gl_to_lds16(Ag + k0 + (size_t)(u * 32) * 1024, Al + u * 2048);
#pragma unroll
    for (int u = 0; u < 2; ++u)
      gl_to_lds16(Bg + k0 + (size_t)(u * 32) * 1024, Bl + u * 2048);
    __syncthreads();
    const bf16x8* AS = (const bf16x8*)As;
    const bf16x8* BS = (const bf16x8*)Bs;
#pragma unroll
    for (int kk = 0; kk < 2; ++kk) {
      const int ck = kk ? c1 : c0;
      bf16x8 af[4], bfr[2];
#pragma unroll
      for (int i = 0; i < 4; i++) af[i] = AS[(wm + i * 16 + lrow) * 8 + ck];
#pragma unroll
      for (int j = 0; j < 2; j++) bfr[j] = BS[(wn + j * 16 + lrow) * 8 + ck];
#pragma unroll
      for (int i = 0; i < 4; i++)
#pragma unroll
        for (int j = 0; j < 2; j++)
          acc[i][j] = __builtin_amdgcn_mfma_f32_16x16x32_bf16(af[i], bfr[j], acc[i][j], 0, 0, 0);
    }
    __syncthreads();
  }

  // acc -> tile (scale + bias). As/Bs dead (loop ended on a barrier).
  float (*tile)[65] = (float(*)[65])usm;
#pragma unroll
  for (int i = 0; i < 4; i++) {
    const int rl0 = wm + i * 16 + quad * 4;
#pragma unroll
    for (int j = 0; j < 2; j++) {
      const int cl = wn + j * 16 + lrow;
      const float badd = bqk[n0 + cl];
#pragma unroll
      for (int r = 0; r < 4; r++)
        tile[rl0 + r][cl] = acc[i][j][r] * scale + badd;
    }
  }
  __syncthreads();

  // column-softmax over the 128 slot rows (identical to softmax_fused body)
  const int c = t & 63, s = t >> 6;
  float mx = -1e30f;
  for (int i = s * 32; i < s * 32 + 32; i++) mx = fmaxf(mx, tile[i][c]);
  cred[s][c] = mx;
  __syncthreads();
  if (s == 0) colmax[c] = fmaxf(fmaxf(cred[0][c], cred[1][c]),
                                fmaxf(cred[2][c], cred[3][c]));
  __syncthreads();
  const float cm = colmax[c];
  float sum = 0.f;
  for (int i = s * 32; i < s * 32 + 32; i++) {
    const float e = expf(tile[i][c] - cm);
    tile[i][c] = e; sum += e;
  }
  cred[s][c] = sum;
  __syncthreads();
  if (s == 0) colinv[c] = 1.f / (cred[0][c] + cred[1][c] + cred[2][c] + cred[3][c]);
  __syncthreads();
  bf16* dst = xcat2 + (size_t)blockIdx.x * 128 * 1536 + blockIdx.y * 64;
#pragma unroll
  for (int p = 0; p < 32; p++) {
    const int i = p * 4 + (t >> 6), cc = t & 63;
    dst[(size_t)i * 1536 + cc] = __float2bfloat16(tile[i][cc] * colinv[cc]);
  }
  if (t < 128) {
    float rs = 0.f;
    for (int cc = 0; cc < 64; cc++) rs += tile[t][cc] * colinv[cc];
    P[((size_t)blockIdx.x * 128 + t) * 8 + blockIdx.y] = rs;
  }
}

// Fused GRU: per 128x64 tile of the [8192 x 1024] update,
//   accN = xcat2[:, 0:512)    @ PTn^T  (i_n pre-act, K=512)
//   accH = xcat2[:, 512:1536) @ Whn^T  (h_n pre-act, K=1024)
// via one B panel Wc = [PTn | Whn] (1024 x 1536, ld 1536). Epilogue:
//   n = tanh(accN + bihn + eps*cn*rinv + r*(accH + bhhn));
//   slots = (1-z)*n + z*prev   (r,z from rz_b; prev from slots_f)
__global__ __launch_bounds__(256, 4) void gemm_gru(
    const bf16* __restrict__ X,     // xcat2, ld 1536
    const bf16* __restrict__ Wc,    // [PTn|Whn], ld 1536
    const float* __restrict__ bihn,
    const float* __restrict__ bhhn,
    const float* __restrict__ cn,   // c[col] (n-gate third)
    const float* __restrict__ rinv, // rowinv[row]
    const bf16* __restrict__ rz,    // sigmoided r|z, ld 2048
    float* __restrict__ slots)      // resid in, out (ld 1024)
{
  __shared__ __align__(16) bf16 As[128 * 64];
  __shared__ __align__(16) bf16 Bs[64 * 64];
  const int t = threadIdx.x;
  const int m0 = blockIdx.x * 128, n0 = blockIdx.y * 64;
  const int wave = t >> 6, lane = t & 63;
  const int wm = (wave >> 1) * 64, wn = (wave & 1) * 32;
  const int lrow = lane & 15, quad = lane >> 4;

  f32x4 accN[4][2] = {};
  f32x4 accH[4][2] = {};

  const int srow = t >> 3;
  const int scol = ((t & 7) ^ (srow & 7)) * 8;
  const bf16* Ag = X + (size_t)(m0 + srow) * 1536 + scol;
  const bf16* Bg = Wc + (size_t)(n0 + srow) * 1536 + scol;
  bf16* Al = As + t * 8;
  bf16* Bl = Bs + t * 8;

  const int r3 = lrow & 7;
  const int c0 = quad ^ r3;
  const int c1 = (4 + quad) ^ r3;

  // ---- phase N: K = [0, 512) -> accN ----
  for (int k0 = 0; k0 < 512; k0 += 64) {
#pragma unroll
    for (int u = 0; u < 4; ++u)
      gl_to_lds16(Ag + k0 + (size_t)(u * 32) * 1536, Al + u * 2048);
#pragma unroll
    for (int u = 0; u < 2; ++u)
      gl_to_lds16(Bg + k0 + (size_t)(u * 32) * 1536, Bl + u * 2048);
    __syncthreads();
    const bf16x8* AS = (const bf16x8*)As;
    const bf16x8* BS = (const bf16x8*)Bs;
#pragma unroll
    for (int kk = 0; kk < 2; ++kk) {
      const int ck = kk ? c1 : c0;
      bf16x8 af[4], bfr[2];
#pragma unroll
      for (int i = 0; i < 4; i++) af[i] = AS[(wm + i * 16 + lrow) * 8 + ck];
#pragma unroll
      for (int j = 0; j < 2; j++) bfr[j] = BS[(wn + j * 16 + lrow) * 8 + ck];
#pragma unroll
      for (int i = 0; i < 4; i++)
#pragma unroll
        for (int j = 0; j < 2; j++)
          accN[i][j] = __builtin_amdgcn_mfma_f32_16x16x32_bf16(af[i], bfr[j], accN[i][j], 0, 0, 0);
    }
    __syncthreads();
  }
  // ---- phase H: K = [512, 1536) -> accH ----
  for (int k0 = 512; k0 < 1536; k0 += 64) {
#pragma unroll
    for (int u = 0; u < 4; ++u)
      gl_to_lds16(Ag + k0 + (size_t)(u * 32) * 1536, Al + u * 2048);
#pragma unroll
    for (int u = 0; u < 2; ++u)
      gl_to_lds16(Bg + k0 + (size_t)(u * 32) * 1536, Bl + u * 2048);
    __syncthreads();
    const bf16x8* AS = (const bf16x8*)As;
    const bf16x8* BS = (const bf16x8*)Bs;
#pragma unroll
    for (int kk = 0; kk < 2; ++kk) {
      const int ck = kk ? c1 : c0;
      bf16x8 af[4], bfr[2];
#pragma unroll
      for (int i = 0; i < 4; i++) af[i] = AS[(wm + i * 16 + lrow) * 8 + ck];
#pragma unroll
      for (int j = 0; j < 2; j++) bfr[j] = BS[(wn + j * 16 + lrow) * 8 + ck];
#pragma unroll
      for (int i = 0; i < 4; i++)
#pragma unroll
        for (int j = 0; j < 2; j++)
          accH[i][j] = __builtin_amdgcn_mfma_f32_16x16x32_bf16(af[i], bfr[j], accH[i][j], 0, 0, 0);
    }
    __syncthreads();
  }

#pragma unroll
  for (int i = 0; i < 4; i++) {
    const int row0 = m0 + wm + i * 16 + quad * 4;
#pragma unroll
    for (int j = 0; j < 2; j++) {
      const int col = n0 + wn + j * 16 + lrow;
      const float bN = bihn[col];
      const float bH = bhhn[col];
      const float cc = cn[col];
#pragma unroll
      for (int r = 0; r < 4; r++) {
        const int row = row0 + r;
        const size_t ridx = (size_t)row * 1024 + col;
        const float vn = accN[i][j][r] + bN + 1e-8f * cc * rinv[row];
        const float vh = accH[i][j][r] + bH;
        const float rg = __bfloat162float(rz[(size_t)row * 2048 + col]);
        const float zg = __bfloat162float(rz[(size_t)row * 2048 + 1024 + col]);
        const float ng = tanhf(vn + rg * vh);
        const float prev = slots[ridx];
        slots[ridx] = (1.f - zg) * ng + zg * prev;
      }
    }
  }
}

// LayerNorm over D=1024, one block per row, bf16 out (stride ldo).
__global__ __launch_bounds__(256) void ln_rows(const float* __restrict__ x,
    const float* __restrict__ g, const float* __restrict__ b,
    bf16* __restrict__ out, int ldo)
{
  const int row = blockIdx.x;
  const int t = threadIdx.x;
  const float* xr = x + (size_t)row * 1024;
  float v[4];
  float s = 0.f, s2 = 0.f;
#pragma unroll
  for (int i = 0; i < 4; i++) {
    float val = xr[t + 256 * i];
    v[i] = val; s += val; s2 += val * val;
  }
#pragma unroll
  for (int off = 32; off > 0; off >>= 1) {
    s  += __shfl_down(s, off);
    s2 += __shfl_down(s2, off);
  }
  __shared__ float rs[4], rs2[4];
  if ((t & 63) == 0) { rs[t >> 6] = s; rs2[t >> 6] = s2; }
  __syncthreads();
  const float S  = rs[0] + rs[1] + rs[2] + rs[3];
  const float S2 = rs2[0] + rs2[1] + rs2[2] + rs2[3];
  const float mean = S * (1.f / 1024.f);
  const float var  = S2 * (1.f / 1024.f) - mean * mean;
  const float rstd = rsqrtf(var + 1e-5f);
  bf16* outr = out + (size_t)row * ldo;
#pragma unroll
  for (int i = 0; i < 4; i++) {
    const int c = t + 256 * i;
    outr[c] = __float2bfloat16((v[i] - mean) * rstd * g[c] + b[c]);
  }
}

// rowinv[m] = 1 / (sum_jt P[m][jt] + 512e-8)
__global__ __launch_bounds__(256) void rowinv_k(const float* __restrict__ P,
                                                float* __restrict__ rowinv)
{
  const int m = blockIdx.x * 256 + threadIdx.x;
  const float* p = P + (size_t)m * 8;
  float s = 0.f;
#pragma unroll
  for (int i = 0; i < 8; i++) s += p[i];
  rowinv[m] = 1.f / (s + 512.f * 1e-8f);
}

// xcat2 sm-columns *= rowinv[m]  (in-place, cols [0,512))
__global__ __launch_bounds__(256) void smscale(bf16* __restrict__ x,
                                               const float* __restrict__ rinv)
{
  const int idx = blockIdx.x * 256 + threadIdx.x;  // M*512
  const int m = idx >> 9, j = idx & 511;
  const size_t a = (size_t)m * 1536 + j;
  x[a] = __float2bfloat16(__bfloat162float(x[a]) * rinv[m]);
}

// slots init: fp32 master + bf16 mirror into xcat2 cols [512,1536).
__global__ __launch_bounds__(256) void init_slots(const float* __restrict__ x,
    float* __restrict__ sf, bf16* __restrict__ xr)
{
  const size_t base = (size_t)blockIdx.x * 1024 + threadIdx.x;
#pragma unroll
  for (int i = 0; i < 4; i++) {
    const size_t idx = base + 256 * i;
    const float v = x[idx];
    sf[idx] = v;
    xr[(idx >> 10) * 1536 + (idx & 1023)] = __float2bfloat16(v);
  }
}

__global__ __launch_bounds__(256) void f2b(const float* __restrict__ x,
                                           bf16* __restrict__ y)
{
  const size_t base = (size_t)blockIdx.x * 1024 + threadIdx.x;
#pragma unroll
  for (int i = 0; i < 4; i++) y[base + 256 * i] = __float2bfloat16(x[base + 256 * i]);
}

// strided f2b: dst[n*dstld + c] = src[n*1024 + c]  (n rows x 1024 cols)
__global__ __launch_bounds__(256) void f2b_ld(const float* __restrict__ src,
                                              bf16* __restrict__ dst, int dstld)
{
  const int idx = blockIdx.x * 256 + threadIdx.x;
  const int n = idx >> 10, c = idx & 1023;
  dst[(size_t)n * dstld + c] = __float2bfloat16(src[(size_t)n * 1024 + c]);
}

// wqT[d][d'] = Wq[d'][d]
__global__ __launch_bounds__(256) void f2b_T(const float* __restrict__ Wq,
                                             bf16* __restrict__ wqT)
{
  const int idx = blockIdx.x * 256 + threadIdx.x;
  const int d = idx >> 10, dp = idx & 1023;
  wqT[idx] = __float2bfloat16(Wq[(size_t)dp * 1024 + d]);
}

__global__ __launch_bounds__(256) void make_brz(const float* __restrict__ bih,
    const float* __restrict__ bhh, float* __restrict__ brz)
{
  const int n = blockIdx.x * 256 + threadIdx.x;
  brz[n] = bih[n] + bhh[n];
}

// bqk[j] = SCALE * <bq, k[j,:]>
__global__ __launch_bounds__(256) void make_bqk(const bf16* __restrict__ k,
    const float* __restrict__ bq, float* __restrict__ bqk, float scale)
{
  const int j = blockIdx.x * 256 + threadIdx.x;
  const bf16* kr = k + (size_t)j * 1024;
  float s = 0.f;
  for (int d = 0; d < 1024; d++) s += bq[d] * __bfloat162float(kr[d]);
  bqk[j] = scale * s;
}

// vcol[d] = sum_j v[j,d]   (v row-major [512][1024])
__global__ __launch_bounds__(256) void make_vcol(const bf16* __restrict__ v,
                                                 float* __restrict__ vcol)
{
  const int d = blockIdx.x * 256 + threadIdx.x;  // 1024
  float s = 0.f;
  for (int j = 0; j < 512; j++) s += __bfloat162float(v[(size_t)j * 1024 + d]);
  vcol[d] = s;
}

// c[n] = sum_d Wih[n,d] * vcol[d]  (block per n, 3072 blocks)
__global__ __launch_bounds__(256) void make_c(const float* __restrict__ Wih,
    const float* __restrict__ vcol, float* __restrict__ c)
{
  const int n = blockIdx.x;
  const int t = threadIdx.x;
  const float* wr = Wih + (size_t)n * 1024;
  float s = 0.f;
#pragma unroll
  for (int i = 0; i < 4; i++) s += wr[t + 256 * i] * vcol[t + 256 * i];
#pragma unroll
  for (int off = 32; off > 0; off >>= 1) s += __shfl_down(s, off);
  __shared__ float rs[4];
  if ((t & 63) == 0) rs[t >> 6] = s;
  __syncthreads();
  if (t == 0) c[n] = rs[0] + rs[1] + rs[2] + rs[3];
}

extern "C" void kernel_launch(void* const* d_in, const int* in_sizes, int n_in,
                              void* d_out, int out_size, void* d_ws, size_t ws_size,
                              hipStream_t stream)
{
  const float* inputs = (const float*)d_in[0];
  const float* texts  = (const float*)d_in[1];
  const float* Wq  = (const float*)d_in[2];  const float* bq  = (const float*)d_in[3];
  const float* Wk  = (const float*)d_in[4];  const float* bk  = (const float*)d_in[5];
  const float* Wv  = (const float*)d_in[6];  const float* bv  = (const float*)d_in[7];
  const float* Wih = (const float*)d_in[8];  const float* bih = (const float*)d_in[9];
  const float* Whh = (const float*)d_in[10]; const float* bhh = (const float*)d_in[11];
  const float* W1  = (const float*)d_in[12]; const float* b1  = (const float*)d_in[13];
  const float* W2  = (const float*)d_in[14]; const float* b2  = (const float*)d_in[15];
  const float* g_in = (const float*)d_in[16]; const float* be_in = (const float*)d_in[17];
  const float* g_sl = (const float*)d_in[18]; const float* be_sl = (const float*)d_in[19];
  const float* g_ff = (const float*)d_in[20]; const float* be_ff = (const float*)d_in[21];

  constexpr int B = 64, N = 128, J = 512, D = 1024, H = 4096;
  constexpr int M = B * N;
  const float SCALE = 0.03125f;

  char* ws = (char*)d_ws;
  size_t off = 0;
  auto alloc = [&](size_t bytes) -> char* {
    char* p = ws + off; off += (bytes + 255) & ~(size_t)255; return p;
  };
  // persistent (~66 MB)
  bf16* wk_b    = (bf16*)alloc((size_t)D * D * 2);         // 2 MB
  bf16* wv_b    = (bf16*)alloc((size_t)D * D * 2);         // 2 MB
  bf16* w1_b    = (bf16*)alloc((size_t)H * D * 2);         // 8 MB
  bf16* w2_b    = (bf16*)alloc((size_t)D * H * 2);         // 8 MB
  bf16* win_b   = (bf16*)alloc((size_t)D * D * 2);         // 2 MB Wih rows 2048:3071
  bf16* wihrz_b = (bf16*)alloc((size_t)2048 * D * 2);      // 4 MB Wih rows 0:2047
  bf16* wqT_b   = (bf16*)alloc((size_t)D * D * 2);         // 2 MB
  bf16* wcat2_b = (bf16*)alloc((size_t)2048 * 1536 * 2);   // 6 MB [PT_rz|Whh_rz]
  bf16* ptnw_b  = (bf16*)alloc((size_t)D * 1536 * 2);      // 3 MB [PT_n|Whn]
  bf16* kq_b    = (bf16*)alloc((size_t)J * D * 2);         // 1 MB
  bf16* texts_n = (bf16*)alloc((size_t)J * D * 2);         // 1 MB
  bf16* k_b     = (bf16*)alloc((size_t)J * D * 2);         // 1 MB
  bf16* v_b     = (bf16*)alloc((size_t)J * D * 2);         // 1 MB
  bf16* xcat2_b = (bf16*)alloc((size_t)M * 1536 * 2);      // 24 MB [sm|slots]
  float* brz_b  = (float*)alloc((size_t)2048 * 4);
  float* bqk_b  = (float*)alloc((size_t)J * 4);
  float* vcol_b = (float*)alloc((size_t)D * 4);
  float* c_b    = (float*)alloc((size_t)3072 * 4);
  float* P_b    = (float*)alloc((size_t)M * 8 * 4);
  float* rinv_b = (float*)alloc((size_t)M * 4);
  // phase-overlapped union U (48 MB):
  //   xln (16 MB) at U      — live ln->dots_sm (attn) / ln->W1/W2 (mlp)
  //   rz  (32 MB) at U      — live rzGEMM->gru (xln dead by then)
  //   h1  (32 MB) at U+16MB — live W1->W2 (rz dead by then)
  char* U = alloc((size_t)48 * 1024 * 1024);
  bf16*  xln_b  = (bf16*)(U);
  bf16*  rz_b   = (bf16*)(U);
  bf16*  h1_b   = (bf16*)(U + (size_t)16 * 1024 * 1024);

  if (ws_size < off) return;  // fail loudly instead of faulting

  float* slots_f = (float*)d_out;

  // ---- weight prep ----
  f2b<<<dim3(D * D / 1024), 256, 0, stream>>>(Wk, wk_b);
  f2b<<<dim3(D * D / 1024), 256, 0, stream>>>(Wv, wv_b);
  f2b<<<dim3(H * D / 1024), 256, 0, stream>>>(W1, w1_b);
  f2b<<<dim3(D * H / 1024), 256, 0, stream>>>(W2, w2_b);
  f2b<<<dim3(D * D / 1024), 256, 0, stream>>>(Wih + (size_t)2048 * D, win_b);
  f2b<<<dim3(2048 * D / 1024), 256, 0, stream>>>(Wih, wihrz_b);
  f2b_T<<<dim3(D * D / 256), 256, 0, stream>>>(Wq, wqT_b);
  // Whh rows 0:2047 -> wcat2 cols [512,1536)
  f2b_ld<<<dim3(2048 * 1024 / 256), 256, 0, stream>>>(Whh, wcat2_b + 512, 1536);
  // Whh rows 2048:3071 (Whn) -> ptnw cols [512,1536)
  f2b_ld<<<dim3(1024 * 1024 / 256), 256, 0, stream>>>(
      Whh + (size_t)2048 * D, ptnw_b + 512, 1536);
  make_brz<<<dim3(8), 256, 0, stream>>>(bih, bhh, brz_b);

  init_slots<<<dim3(M * D / 1024), 256, 0, stream>>>(inputs, slots_f, xcat2_b + 512);

  // ---- iteration-invariant tensors ----
  ln_rows<<<dim3(J), 256, 0, stream>>>(texts, g_in, be_in, texts_n, D);
  gemm_bt<64><<<dim3(J / 128, D / 64), 256, 0, stream>>>(
      texts_n, D, wk_b, D, bk, J, D, D, 1.f, 0,
      nullptr, 0, k_b, D, nullptr, nullptr, nullptr);
  gemm_bt<64><<<dim3(J / 128, D / 64), 256, 0, stream>>>(
      texts_n, D, wv_b, D, bv, J, D, D, 1.f, 0,
      nullptr, 0, v_b, D, nullptr, nullptr, nullptr);
  gemm_bt<64><<<dim3(J / 128, D / 64), 256, 0, stream>>>(
      k_b, D, wqT_b, D, nullptr, J, D, D, 1.f, 0,
      nullptr, 0, kq_b, D, nullptr, nullptr, nullptr);
  // PT_rz = Wih_rz @ v^T -> wcat2 cols [0,512)
  gemm_bt<64><<<dim3(2048 / 128, J / 64), 256, 0, stream>>>(
      wihrz_b, D, v_b, D, nullptr, 2048, J, D, 1.f, 0,
      nullptr, 0, wcat2_b, 1536, nullptr, nullptr, nullptr);
  // PT_n = Wih_n @ v^T -> ptnw cols [0,512)
  gemm_bt<64><<<dim3(D / 128, J / 64), 256, 0, stream>>>(
      win_b, D, v_b, D, nullptr, D, J, D, 1.f, 0,
      nullptr, 0, ptnw_b, 1536, nullptr, nullptr, nullptr);
  make_bqk<<<dim3(2), 256, 0, stream>>>(k_b, bq, bqk_b, SCALE);
  make_vcol<<<dim3(4), 256, 0, stream>>>(v_b, vcol_b);
  make_c<<<dim3(3072), 256, 0, stream>>>(Wih, vcol_b, c_b);

  for (int it = 0; it < 3; it++) {
    // xln = LN(slots)
    ln_rows<<<dim3(M), 256, 0, stream>>>(slots_f, g_sl, be_sl, xln_b, D);
    // fused dots+softmax -> xcat2 cols [0,512) + P partials
    dots_sm<<<dim3(M / 128, J / 64), 256, 0, stream>>>(
        xln_b, kq_b, bqk_b, SCALE, xcat2_b, P_b);
    rowinv_k<<<dim3(M / 256), 256, 0, stream>>>(P_b, rinv_b);
    smscale<<<dim3(M * 512 / 256), 256, 0, stream>>>(xcat2_b, rinv_b);
    // rz = sigmoid([sm2|slots] @ [PT_rz|Whh_rz]^T + brz + eps*rinv*c_rz)
    // (xln dead now; rz overlays U)
    gemm_bt<128><<<dim3(M / 128, 2048 / 128), 256, 0, stream>>>(
        xcat2_b, 1536, wcat2_b, 1536, brz_b, M, 2048, 1536, 1.f, F_SIGMOID | F_EPSC,
        nullptr, 0, rz_b, 2048, nullptr, c_b, rinv_b);
    // fused GRU: accN (sm2@PTn) + accH (slots@Whn) + gate epilogue -> slots_f
    gemm_gru<<<dim3(M / 128, D / 64), 256, 0, stream>>>(
        xcat2_b, ptnw_b, bih + 2048, bhh + 2048, c_b + 2048, rinv_b,
        rz_b, slots_f);
    // MLP residual, H split into two 2048 halves (rz dead after gru)
    ln_rows<<<dim3(M), 256, 0, stream>>>(slots_f, g_ff, be_ff, xln_b, D);
    gemm_bt<128><<<dim3(M / 128, 2048 / 128), 256, 0, stream>>>(
        xln_b, D, w1_b, D, b1, M, 2048, D, 1.f, F_RELU,
        nullptr, 0, h1_b, 2048, nullptr, nullptr, nullptr);
    gemm_bt<64><<<dim3(M / 128, D / 64), 256, 0, stream>>>(
        h1_b, 2048, w2_b, H, b2, M, D, 2048, 1.f, 0,
        slots_f, D, nullptr, 0, slots_f, nullptr, nullptr);
    gemm_bt<128><<<dim3(M / 128, 2048 / 128), 256, 0, stream>>>(
        xln_b, D, w1_b + (size_t)2048 * D, D, b1 + 2048, M, 2048, D, 1.f, F_RELU,
        nullptr, 0, h1_b, 2048, nullptr, nullptr, nullptr);
    gemm_bt<64><<<dim3(M / 128, D / 64), 256, 0, stream>>>(
        h1_b, 2048, w2_b + 2048, H, nullptr, M, D, 2048, 1.f, 0,
        slots_f, D, xcat2_b + 512, 1536, slots_f, nullptr, nullptr);
  }
}